// Round 2
// baseline (238.055 us; speedup 1.0000x reference)
//
#include <hip/hip_runtime.h>

// cumprod along dim 1 of (ROWS, N) fp32, row-major.
// One 256-thread block per row. Thread-blocked layout: thread t owns
// elements [t*32, t*32+32) entirely in registers (no big-LDS round trip).
// Per-lane contiguous 128B => every fetched line fully consumed.

#define N      8192
#define T      256
#define CHUNK  32   // N / T

__global__ __launch_bounds__(T) void cumprod_rows_kernel(
    const float* __restrict__ x, float* __restrict__ out, int n_rows)
{
    __shared__ float wtot[T / 64];   // per-wave chunk-product totals

    const int row = blockIdx.x;
    if (row >= n_rows) return;
    const int tid  = threadIdx.x;
    const int lane = tid & 63;
    const int wid  = tid >> 6;

    const float* __restrict__ xr   = x   + (size_t)row * N + (size_t)tid * CHUNK;
    float*       __restrict__ outr = out + (size_t)row * N + (size_t)tid * CHUNK;

    // ---- Load 32 contiguous elements as 8 independent float4s ----
    float vals[CHUNK];
    const float4* __restrict__ src = reinterpret_cast<const float4*>(xr);
#pragma unroll
    for (int i = 0; i < CHUNK / 4; ++i) {
        const float4 d = src[i];
        vals[4 * i + 0] = d.x; vals[4 * i + 1] = d.y;
        vals[4 * i + 2] = d.z; vals[4 * i + 3] = d.w;
    }

    // ---- Local inclusive product scan in registers ----
    float p = 1.0f;
#pragma unroll
    for (int j = 0; j < CHUNK; ++j) { p *= vals[j]; vals[j] = p; }

    // ---- Wave-level inclusive product scan of chunk totals ----
    float inc = p;
#pragma unroll
    for (int off = 1; off < 64; off <<= 1) {
        const float o = __shfl_up(inc, off, 64);
        if (lane >= off) inc *= o;
    }
    if (lane == 63) wtot[wid] = inc;
    __syncthreads();

    // ---- Exclusive prefix for this thread ----
    float excl = __shfl_up(inc, 1, 64);
    if (lane == 0) excl = 1.0f;
#pragma unroll
    for (int w = 0; w < T / 64; ++w)
        if (w < wid) excl *= wtot[w];

    // ---- Apply prefix and store as float4 ----
    float4* __restrict__ dst = reinterpret_cast<float4*>(outr);
#pragma unroll
    for (int i = 0; i < CHUNK / 4; ++i) {
        float4 d;
        d.x = vals[4 * i + 0] * excl; d.y = vals[4 * i + 1] * excl;
        d.z = vals[4 * i + 2] * excl; d.w = vals[4 * i + 3] * excl;
        dst[i] = d;
    }
}

extern "C" void kernel_launch(void* const* d_in, const int* in_sizes, int n_in,
                              void* d_out, int out_size, void* d_ws, size_t ws_size,
                              hipStream_t stream)
{
    const float* x   = (const float*)d_in[0];
    float*       out = (float*)d_out;
    const int n_rows = in_sizes[0] / N;   // 4096
    cumprod_rows_kernel<<<n_rows, T, 0, stream>>>(x, out, n_rows);
}

// Round 3
// 230.245 us; speedup vs baseline: 1.0339x; 1.0339x over previous
//
#include <hip/hip_runtime.h>

// cumprod along dim 1 of (ROWS, N) fp32, row-major.
// One 256-thread block per row. Wave w owns contiguous [w*2048,(w+1)*2048);
// 8 segments of 256 elems per wave; lane l holds 4 contiguous floats/segment.
// => every global_load/store_dwordx4 is perfectly coalesced (64x16B contiguous).

#define N     8192
#define T     256
#define NW    (T / 64)      // 4 waves
#define WE    (N / NW)      // 2048 elems per wave
#define SEGS  8             // segments per wave
#define SE    (WE / SEGS)   // 256 elems per segment

__global__ __launch_bounds__(T, 6) void cumprod_rows_kernel(
    const float* __restrict__ x, float* __restrict__ out, int n_rows)
{
    __shared__ float wtot[NW];

    const int row  = blockIdx.x;
    if (row >= n_rows) return;
    const int tid  = threadIdx.x;
    const int lane = tid & 63;
    const int wid  = tid >> 6;

    const size_t base = (size_t)row * N + (size_t)wid * WE + (size_t)lane * 4;
    const float* __restrict__ xr   = x   + base;
    float*       __restrict__ outr = out + base;

    // ---- Issue all 8 coalesced float4 loads up front ----
    float v[SEGS][4];
#pragma unroll
    for (int s = 0; s < SEGS; ++s) {
        const float4 d = *reinterpret_cast<const float4*>(xr + s * SE);
        v[s][0] = d.x; v[s][1] = d.y; v[s][2] = d.z; v[s][3] = d.w;
    }

    // ---- Local inclusive scan of each lane's 4 elements ----
    float linc[SEGS];
#pragma unroll
    for (int s = 0; s < SEGS; ++s) {
        v[s][1] *= v[s][0];
        v[s][2] *= v[s][1];
        v[s][3] *= v[s][2];
        linc[s] = v[s][3];
    }

    // ---- 8 independent wave-level inclusive scans (interleaved for ILP) ----
#pragma unroll
    for (int off = 1; off < 64; off <<= 1) {
#pragma unroll
        for (int s = 0; s < SEGS; ++s) {
            const float o = __shfl_up(linc[s], off, 64);
            if (lane >= off) linc[s] *= o;
        }
    }

    // ---- Per-segment exclusive prefix + segment totals (shfls independent) ----
    float e[SEGS], t[SEGS];
#pragma unroll
    for (int s = 0; s < SEGS; ++s) {
        t[s] = __shfl(linc[s], 63, 64);
        float ee = __shfl_up(linc[s], 1, 64);
        e[s] = (lane == 0) ? 1.0f : ee;
    }

    // ---- Serial carry across segments (8 muls) ----
    float carry = 1.0f;
#pragma unroll
    for (int s = 0; s < SEGS; ++s) {
        e[s] *= carry;      // exclusive prefix incl. prior segments
        carry *= t[s];
    }
    // carry == wave total

    if (lane == 0) wtot[wid] = carry;
    __syncthreads();

    float wpre = 1.0f;
#pragma unroll
    for (int w = 0; w < NW; ++w)
        if (w < wid) wpre *= wtot[w];

    // ---- Apply prefixes, coalesced float4 stores ----
#pragma unroll
    for (int s = 0; s < SEGS; ++s) {
        const float m = e[s] * wpre;
        float4 d;
        d.x = v[s][0] * m; d.y = v[s][1] * m;
        d.z = v[s][2] * m; d.w = v[s][3] * m;
        *reinterpret_cast<float4*>(outr + s * SE) = d;
    }
}

extern "C" void kernel_launch(void* const* d_in, const int* in_sizes, int n_in,
                              void* d_out, int out_size, void* d_ws, size_t ws_size,
                              hipStream_t stream)
{
    const float* x   = (const float*)d_in[0];
    float*       out = (float*)d_out;
    const int n_rows = in_sizes[0] / N;   // 4096
    cumprod_rows_kernel<<<n_rows, T, 0, stream>>>(x, out, n_rows);
}

// Round 4
// 229.727 us; speedup vs baseline: 1.0363x; 1.0023x over previous
//
#include <hip/hip_runtime.h>

// cumprod along dim 1 of (ROWS, N) fp32, row-major.
// One 256-thread block per row. Wave w owns contiguous [w*2048,(w+1)*2048);
// 8 segments of 256 elems per wave; lane l holds 4 contiguous floats/segment.
// All 8 coalesced float4 loads are forced to issue BEFORE any consumption
// (sched_barrier) so the wave has 8 loads in flight (vmcnt pipelining),
// instead of the compiler's 28-VGPR serialized reuse of 2 load registers.

#define N     8192
#define T     256
#define NW    (T / 64)      // 4 waves
#define WE    (N / NW)      // 2048 elems per wave
#define SEGS  8             // segments per wave
#define SE    (WE / SEGS)   // 256 elems per segment

__global__ __launch_bounds__(T) void cumprod_rows_kernel(
    const float* __restrict__ x, float* __restrict__ out, int n_rows)
{
    __shared__ float wtot[NW];

    const int row  = blockIdx.x;
    if (row >= n_rows) return;
    const int tid  = threadIdx.x;
    const int lane = tid & 63;
    const int wid  = tid >> 6;

    const size_t base = (size_t)row * N + (size_t)wid * WE + (size_t)lane * 4;
    const float* __restrict__ xr   = x   + base;
    float*       __restrict__ outr = out + base;

    // ---- Issue ALL 8 coalesced float4 loads up front; pin them there ----
    float4 d[SEGS];
    const float4* __restrict__ src = reinterpret_cast<const float4*>(xr);
#pragma unroll
    for (int s = 0; s < SEGS; ++s) d[s] = src[s * (SE / 4)];
    __builtin_amdgcn_sched_barrier(0);   // loads may not sink past this point

    // ---- Local inclusive scan of each lane's 4 elements ----
    float v[SEGS][4];
    float linc[SEGS];
#pragma unroll
    for (int s = 0; s < SEGS; ++s) {
        v[s][0] = d[s].x;
        v[s][1] = d[s].y * v[s][0];
        v[s][2] = d[s].z * v[s][1];
        v[s][3] = d[s].w * v[s][2];
        linc[s] = v[s][3];
    }

    // ---- 8 independent wave-level inclusive scans (interleaved for ILP) ----
#pragma unroll
    for (int off = 1; off < 64; off <<= 1) {
#pragma unroll
        for (int s = 0; s < SEGS; ++s) {
            const float o = __shfl_up(linc[s], off, 64);
            if (lane >= off) linc[s] *= o;
        }
    }

    // ---- Per-segment exclusive prefix + segment totals ----
    float e[SEGS], t[SEGS];
#pragma unroll
    for (int s = 0; s < SEGS; ++s) {
        t[s] = __shfl(linc[s], 63, 64);
        const float ee = __shfl_up(linc[s], 1, 64);
        e[s] = (lane == 0) ? 1.0f : ee;
    }

    // ---- Serial carry across segments (8 muls) ----
    float carry = 1.0f;
#pragma unroll
    for (int s = 0; s < SEGS; ++s) {
        e[s] *= carry;
        carry *= t[s];
    }

    if (lane == 0) wtot[wid] = carry;
    __syncthreads();

    float wpre = 1.0f;
#pragma unroll
    for (int w = 0; w < NW; ++w)
        if (w < wid) wpre *= wtot[w];

    // ---- Apply prefixes, coalesced float4 stores ----
#pragma unroll
    for (int s = 0; s < SEGS; ++s) {
        const float m = e[s] * wpre;
        float4 o;
        o.x = v[s][0] * m; o.y = v[s][1] * m;
        o.z = v[s][2] * m; o.w = v[s][3] * m;
        *reinterpret_cast<float4*>(outr + s * SE) = o;
    }
}

extern "C" void kernel_launch(void* const* d_in, const int* in_sizes, int n_in,
                              void* d_out, int out_size, void* d_ws, size_t ws_size,
                              hipStream_t stream)
{
    const float* x   = (const float*)d_in[0];
    float*       out = (float*)d_out;
    const int n_rows = in_sizes[0] / N;   // 4096
    cumprod_rows_kernel<<<n_rows, T, 0, stream>>>(x, out, n_rows);
}